// Round 4
// baseline (557.292 us; speedup 1.0000x reference)
//
#include <hip/hip_runtime.h>

// Problem constants: B=4, S=2048, D=1024, H=16, DK=64
#define BDIM 4
#define SDIM 2048
#define DDIM 1024
#define HDIM 16
#define DKDIM 64
#define MDIM (BDIM*SDIM)   // 8192

typedef __attribute__((ext_vector_type(8))) short bf16x8_t;
typedef __attribute__((ext_vector_type(4))) float f32x4_t;

__device__ __forceinline__ unsigned short f2bf(float f) {
    union { float f; unsigned u; } v; v.f = f;
    unsigned r = v.u + 0x7FFFu + ((v.u >> 16) & 1u);  // RNE
    return (unsigned short)(r >> 16);
}

__device__ __forceinline__ unsigned pkbf(float a, float b) {
#if defined(__has_builtin) && __has_builtin(__builtin_amdgcn_cvt_pk_bf16_f32)
    auto v = __builtin_amdgcn_cvt_pk_bf16_f32(a, b);
    union { decltype(v) x; unsigned u; } cv; cv.x = v; return cv.u;
#else
    return (unsigned)f2bf(a) | ((unsigned)f2bf(b) << 16);
#endif
}

__device__ __forceinline__ float bflo(unsigned u) {
    union { unsigned u; float f; } v; v.u = u << 16; return v.f;
}
__device__ __forceinline__ float bfhi(unsigned u) {
    union { unsigned u; float f; } v; v.u = u & 0xFFFF0000u; return v.f;
}

#if defined(__has_builtin) && __has_builtin(__builtin_amdgcn_exp2f)
#define EXP2F(x) __builtin_amdgcn_exp2f(x)
#else
#define EXP2F(x) __expf((x) * 0.69314718f)
#endif

#define QSCALE 0.18033688011112042f  // log2(e)/8, folded into Q projection

__device__ __forceinline__ void gl_lds16(const void* g, void* l) {
    __builtin_amdgcn_global_load_lds(
        (const __attribute__((address_space(1))) unsigned int*)g,
        (__attribute__((address_space(3))) unsigned int*)l, 16, 0, 0);
}

// ---------------- fp32 -> bf16 casts (batched) ----------------
__global__ void cvt3(const float* __restrict__ a, const float* __restrict__ b, const float* __restrict__ c,
                     unsigned short* __restrict__ oa, unsigned short* __restrict__ ob, unsigned short* __restrict__ oc,
                     int n4) {
    int i = blockIdx.x * blockDim.x + threadIdx.x;
    const float* s = blockIdx.y == 0 ? a : (blockIdx.y == 1 ? b : c);
    unsigned short* d = blockIdx.y == 0 ? oa : (blockIdx.y == 1 ? ob : oc);
    if (i < n4) {
        float4 v = ((const float4*)s)[i];
        ushort4 o;
        o.x = f2bf(v.x); o.y = f2bf(v.y); o.z = f2bf(v.z); o.w = f2bf(v.w);
        ((ushort4*)d)[i] = o;
    }
}

__global__ void cvt4(const float* __restrict__ a, const float* __restrict__ b,
                     const float* __restrict__ c, const float* __restrict__ e,
                     unsigned short* __restrict__ oa, unsigned short* __restrict__ ob,
                     unsigned short* __restrict__ oc, unsigned short* __restrict__ oe,
                     int n4) {
    int i = blockIdx.x * blockDim.x + threadIdx.x;
    const float* s = blockIdx.y == 0 ? a : (blockIdx.y == 1 ? b : (blockIdx.y == 2 ? c : e));
    unsigned short* d = blockIdx.y == 0 ? oa : (blockIdx.y == 1 ? ob : (blockIdx.y == 2 ? oc : oe));
    if (i < n4) {
        float4 v = ((const float4*)s)[i];
        ushort4 o;
        o.x = f2bf(v.x); o.y = f2bf(v.y); o.z = f2bf(v.z); o.w = f2bf(v.w);
        ((ushort4*)d)[i] = o;
    }
}

// ---------------- mask -> transposed bf16 addend: Madd[b][k][q] = m ? 0 : -1e9 ----------------
__global__ __launch_bounds__(256) void mask_t(const int* __restrict__ m, unsigned short* __restrict__ Madd) {
    __shared__ unsigned short T[64][68];  // [k][q], pad 68 (136 B rows, 8B-aligned)
    const int t = threadIdx.x;
    const int k0 = blockIdx.x * 64, q0 = blockIdx.y * 64, b = blockIdx.z;
    const int lane = t & 63, wv = t >> 6;
#pragma unroll
    for (int i = 0; i < 16; ++i) {
        const int q = wv * 16 + i;
        const int v = m[((size_t)b * SDIM + q0 + q) * SDIM + k0 + lane];
        T[lane][q] = v ? (unsigned short)0 : (unsigned short)0xCE6Eu;  // bf16(-1e9)
    }
    __syncthreads();
    const int k = t >> 2, qc = t & 3;
#pragma unroll
    for (int j = 0; j < 4; ++j) {
        const int q = qc * 16 + j * 4;
        ushort4 o = *(const ushort4*)&T[k][q];
        *(ushort4*)&Madd[((size_t)b * SDIM + k0 + k) * SDIM + q0 + q] = o;
    }
}

// ---------------- NT GEMM: C[M,N] = (A[M,K] @ B[N,K]^T + bias) * scale ----------------
// OMODE 0: bf16 row-major; 1: bf16 transposed (C^T); 2: f32 row-major
// LDS tiles XOR-swizzled: row r's 16B chunk c holds global chunk c ^ ((r>>1)&3).
template<int OMODE>
__global__ __launch_bounds__(256) void gemm_nt(
    const unsigned short* __restrict__ A,
    const unsigned short* __restrict__ B,
    const float* __restrict__ bias,
    unsigned short* __restrict__ Cb,
    float* __restrict__ Cf,
    int M, int N, int K, float scale)
{
    __shared__ unsigned short As[128 * 32];
    __shared__ unsigned short Bs[128 * 32];
    const int tid = threadIdx.x;
    const int w = tid >> 6, lane = tid & 63;
    const int wr = w >> 1, wc = w & 1;
    const int quad = lane >> 4, l16 = lane & 15;
    const int bn = blockIdx.x, bm = blockIdx.y;

    const int rl = lane >> 2;
    const int cl = (((lane & 3) ^ ((rl >> 1) & 3)) * 8);  // swizzled source column
    const int sw = (l16 >> 1) & 3;                        // reader swizzle
    const int c0 = w * 2;
    const unsigned short* gA = A + (size_t)(bm * 128 + c0 * 16 + rl) * K + cl;
    const unsigned short* gB = B + (size_t)(bn * 128 + c0 * 16 + rl) * K + cl;
    unsigned short* lA = As + c0 * 512 + lane * 8;
    unsigned short* lB = Bs + c0 * 512 + lane * 8;

    f32x4_t acc[4][4] = {};

    for (int k0 = 0; k0 < K; k0 += 32) {
        gl_lds16(gA, lA);
        gl_lds16(gA + (size_t)16 * K, lA + 16 * 32);
        gl_lds16(gB, lB);
        gl_lds16(gB + (size_t)16 * K, lB + 16 * 32);
        gA += 32; gB += 32;
        __syncthreads();
        bf16x8_t af[4], bfr[4];
#pragma unroll
        for (int mi = 0; mi < 4; ++mi)
            af[mi] = *(const bf16x8_t*)(As + (wr * 64 + mi * 16 + l16) * 32 + (quad ^ sw) * 8);
#pragma unroll
        for (int ni = 0; ni < 4; ++ni)
            bfr[ni] = *(const bf16x8_t*)(Bs + (wc * 64 + ni * 16 + l16) * 32 + (quad ^ sw) * 8);
#pragma unroll
        for (int mi = 0; mi < 4; ++mi)
#pragma unroll
            for (int ni = 0; ni < 4; ++ni)
                acc[mi][ni] = __builtin_amdgcn_mfma_f32_16x16x32_bf16(af[mi], bfr[ni], acc[mi][ni], 0, 0, 0);
        __syncthreads();
    }

#pragma unroll
    for (int mi = 0; mi < 4; ++mi) {
#pragma unroll
        for (int ni = 0; ni < 4; ++ni) {
            const int n = bn * 128 + wc * 64 + ni * 16 + l16;
            const int m0 = bm * 128 + wr * 64 + mi * 16 + quad * 4;
            const float bv = bias[n];
            if (OMODE == 1) {
                ushort4 pk;
                pk.x = f2bf((acc[mi][ni][0] + bv) * scale);
                pk.y = f2bf((acc[mi][ni][1] + bv) * scale);
                pk.z = f2bf((acc[mi][ni][2] + bv) * scale);
                pk.w = f2bf((acc[mi][ni][3] + bv) * scale);
                *(ushort4*)(Cb + (size_t)n * M + m0) = pk;
            } else {
#pragma unroll
                for (int r = 0; r < 4; ++r) {
                    const float v = (acc[mi][ni][r] + bv) * scale;
                    if (OMODE == 0) Cb[(size_t)(m0 + r) * N + n] = f2bf(v);
                    else            Cf[(size_t)(m0 + r) * N + n] = v;
                }
            }
        }
    }
}

// ---------------- fused flash attention (fixed-max softmax, mask in C-init, swizzled LDS) ----------------
__global__ __launch_bounds__(256) void attn_kernel(
    const unsigned short* __restrict__ Qp,   // [M][D] bf16, pre-scaled by log2e/8
    const unsigned short* __restrict__ Kp,   // [M][D] bf16
    const unsigned short* __restrict__ Vt,   // [D][M] bf16 (V^T)
    const unsigned short* __restrict__ Madd, // [B][S(k)][S(q)] bf16: 0 or -1e9
    unsigned short* __restrict__ Xa)         // [M][D] bf16
{
    __shared__ unsigned short Ks[2 * 64 * 32];
    __shared__ unsigned short Vs[2 * 64 * 32];
    __shared__ __align__(16) float Pf[4][2][2][16][36];

    const int tid = threadIdx.x, w = tid >> 6, lane = tid & 63;
    const int quad = lane >> 4, l16 = lane & 15;
    const int bx = blockIdx.x;
    const int h = bx & 15, qt = (bx >> 4) & 15, b = bx >> 8;
    const int q0 = qt * 128;
    const int rl = lane >> 2;
    const int cl = (((lane & 3) ^ ((rl >> 1) & 3)) * 8);
    const int sw = (l16 >> 1) & 3;

    // ---- stage 128x64 Q tile (swizzled), pull A-frags to registers ----
#pragma unroll
    for (int i = 0; i < 4; ++i) {
        const int cc = w * 4 + i;
        const int row = b * SDIM + q0 + (cc & 7) * 16 + rl;
        const int col = h * 64 + (cc >> 3) * 32 + cl;
        unsigned short* dst = (cc < 8 ? Ks + cc * 512 : Vs + (cc - 8) * 512) + lane * 8;
        gl_lds16(Qp + (size_t)row * DDIM + col, dst);
    }
    __syncthreads();
    bf16x8_t aq[2][2];  // [row-group g][kk]
#pragma unroll
    for (int g = 0; g < 2; ++g) {
        aq[g][0] = *(const bf16x8_t*)(Ks + (w * 2 + g) * 512 + l16 * 32 + (quad ^ sw) * 8);
        aq[g][1] = *(const bf16x8_t*)(Vs + (w * 2 + g) * 512 + l16 * 32 + (quad ^ sw) * 8);
    }

    // mask addend base: element (k, q) at Madd[(b*S + k)*S + q]
    const unsigned short* mbase =
        Madd + (size_t)b * SDIM * SDIM + q0 + w * 32 + quad * 4;

    f32x4_t o[2][4] = {};
    f32x4_t o4[2] = {};
    union { unsigned u[4]; bf16x8_t v; } ones;
    ones.u[0] = ones.u[1] = ones.u[2] = ones.u[3] = 0x3F803F80u;

    for (int kt = 0; kt < SDIM / 64; ++kt) {
        __syncthreads();
#pragma unroll
        for (int i = 0; i < 2; ++i) {
            const int cc = w * 2 + i;
            const int rowk = b * SDIM + kt * 64 + (cc & 3) * 16 + rl;
            const int colk = h * 64 + (cc >> 2) * 32 + cl;
            gl_lds16(Kp + (size_t)rowk * DDIM + colk, Ks + cc * 512 + lane * 8);
            const int rowv = h * 64 + (cc & 3) * 16 + rl;
            const int colv = b * SDIM + kt * 64 + (cc >> 2) * 32 + cl;
            gl_lds16(Vt + (size_t)rowv * MDIM + colv, Vs + cc * 512 + lane * 8);
        }
        __syncthreads();

        // C-init from mask addend: 8B load + shift-unpack per (g,ni); no per-score branches
        f32x4_t sf[2][4];
#pragma unroll
        for (int ni = 0; ni < 4; ++ni) {
            const unsigned short* mrow = mbase + (size_t)(kt * 64 + ni * 16 + l16) * SDIM;
#pragma unroll
            for (int g = 0; g < 2; ++g) {
                const uint2 md = *(const uint2*)(mrow + g * 16);
                sf[g][ni][0] = bflo(md.x);
                sf[g][ni][1] = bfhi(md.x);
                sf[g][ni][2] = bflo(md.y);
                sf[g][ni][3] = bfhi(md.y);
            }
        }

        // S = Q K^T + Madd
#pragma unroll
        for (int kk = 0; kk < 2; ++kk) {
#pragma unroll
            for (int ni = 0; ni < 4; ++ni) {
                const bf16x8_t bk = *(const bf16x8_t*)(Ks + kk * 2048 + (ni * 16 + l16) * 32 + (quad ^ sw) * 8);
                sf[0][ni] = __builtin_amdgcn_mfma_f32_16x16x32_bf16(aq[0][kk], bk, sf[0][ni], 0, 0, 0);
                sf[1][ni] = __builtin_amdgcn_mfma_f32_16x16x32_bf16(aq[1][kk], bk, sf[1][ni], 0, 0, 0);
            }
        }

        // p = exp2(s); P to per-wave LDS (f32, C-layout)
#pragma unroll
        for (int g = 0; g < 2; ++g) {
#pragma unroll
            for (int r = 0; r < 4; ++r) {
                const int row = quad * 4 + r;
                Pf[w][g][0][row][l16]      = EXP2F(sf[g][0][r]);
                Pf[w][g][0][row][16 + l16] = EXP2F(sf[g][1][r]);
                Pf[w][g][1][row][l16]      = EXP2F(sf[g][2][r]);
                Pf[w][g][1][row][16 + l16] = EXP2F(sf[g][3][r]);
            }
        }

        // P (C-layout) -> A-frags via per-wave LDS; PV + ones-column row-sum
#pragma unroll
        for (int kk = 0; kk < 2; ++kk) {
            bf16x8_t bvf[4];
#pragma unroll
            for (int ni = 0; ni < 4; ++ni)
                bvf[ni] = *(const bf16x8_t*)(Vs + kk * 2048 + (ni * 16 + l16) * 32 + (quad ^ sw) * 8);
#pragma unroll
            for (int g = 0; g < 2; ++g) {
                const float* pr = &Pf[w][g][kk][l16][quad * 8];
                const float4 pa = *(const float4*)pr;
                const float4 pb = *(const float4*)(pr + 4);
                union { unsigned u[4]; bf16x8_t v; } fu;
                fu.u[0] = pkbf(pa.x, pa.y);
                fu.u[1] = pkbf(pa.z, pa.w);
                fu.u[2] = pkbf(pb.x, pb.y);
                fu.u[3] = pkbf(pb.z, pb.w);
#pragma unroll
                for (int ni = 0; ni < 4; ++ni)
                    o[g][ni] = __builtin_amdgcn_mfma_f32_16x16x32_bf16(fu.v, bvf[ni], o[g][ni], 0, 0, 0);
                o4[g] = __builtin_amdgcn_mfma_f32_16x16x32_bf16(fu.v, ones.v, o4[g], 0, 0, 0);
            }
        }
    }

    // finalize
#pragma unroll
    for (int g = 0; g < 2; ++g) {
        float rcp[4];
#pragma unroll
        for (int r = 0; r < 4; ++r) rcp[r] = 1.0f / o4[g][r];
#pragma unroll
        for (int ni = 0; ni < 4; ++ni)
#pragma unroll
            for (int r = 0; r < 4; ++r) {
                const int qg = q0 + w * 32 + g * 16 + quad * 4 + r;
                const int cg = h * 64 + ni * 16 + l16;
                Xa[((size_t)b * SDIM + qg) * DDIM + cg] = f2bf(o[g][ni][r] * rcp[r]);
            }
    }
}

extern "C" void kernel_launch(void* const* d_in, const int* in_sizes, int n_in,
                              void* d_out, int out_size, void* d_ws, size_t ws_size,
                              hipStream_t stream)
{
    const float* query = (const float*)d_in[0];
    const float* key   = (const float*)d_in[1];
    const float* value = (const float*)d_in[2];
    const int*   mask  = (const int*)d_in[3];
    const float* Wq = (const float*)d_in[4];  const float* bq = (const float*)d_in[5];
    const float* Wk = (const float*)d_in[6];  const float* bk = (const float*)d_in[7];
    const float* Wv = (const float*)d_in[8];  const float* bv = (const float*)d_in[9];
    const float* Wo = (const float*)d_in[10]; const float* bo = (const float*)d_in[11];

    const size_t MD = (size_t)MDIM * DDIM;
    const size_t DD = (size_t)DDIM * DDIM;

    unsigned short* qb  = (unsigned short*)d_ws;
    unsigned short* kb  = qb + MD;
    unsigned short* vb  = kb + MD;
    unsigned short* wqb = vb + MD;
    unsigned short* wkb = wqb + DD;
    unsigned short* wvb = wkb + DD;
    unsigned short* wob = wvb + DD;
    unsigned short* Qp  = wob + DD;
    unsigned short* Kp  = Qp + MD;
    unsigned short* Vt  = Kp + MD;
    unsigned short* Xa  = Vt + MD;
    // Madd (B*S*S bf16 = 33.6 MB) overlays qb+kb (exactly 2*MD), dead after Q/K GEMMs
    unsigned short* Madd = qb;

    {
        const int n4m = (int)(MD / 4), n4d = (int)(DD / 4);
        dim3 g3((n4m + 255) / 256, 3), g4((n4d + 255) / 256, 4);
        cvt3<<<g3, 256, 0, stream>>>(query, key, value, qb, kb, vb, n4m);
        cvt4<<<g4, 256, 0, stream>>>(Wq, Wk, Wv, Wo, wqb, wkb, wvb, wob, n4d);
    }

    dim3 gg(DDIM / 128, MDIM / 128);
    gemm_nt<0><<<gg, 256, 0, stream>>>(qb, wqb, bq, Qp, nullptr, MDIM, DDIM, DDIM, QSCALE);
    gemm_nt<0><<<gg, 256, 0, stream>>>(kb, wkb, bk, Kp, nullptr, MDIM, DDIM, DDIM, 1.0f);
    gemm_nt<1><<<gg, 256, 0, stream>>>(vb, wvb, bv, Vt, nullptr, MDIM, DDIM, DDIM, 1.0f);

    mask_t<<<dim3(SDIM / 64, SDIM / 64, BDIM), 256, 0, stream>>>(mask, Madd);

    attn_kernel<<<BDIM * HDIM * (SDIM / 128), 256, 0, stream>>>(Qp, Kp, Vt, Madd, Xa);

    gemm_nt<2><<<gg, 256, 0, stream>>>(Xa, wob, bo, nullptr, (float*)d_out, MDIM, DDIM, DDIM, 1.0f);
}

// Round 5
// 490.186 us; speedup vs baseline: 1.1369x; 1.1369x over previous
//
#include <hip/hip_runtime.h>

// Problem constants: B=4, S=2048, D=1024, H=16, DK=64
#define BDIM 4
#define SDIM 2048
#define DDIM 1024
#define HDIM 16
#define DKDIM 64
#define MDIM (BDIM*SDIM)   // 8192

typedef __attribute__((ext_vector_type(8))) short bf16x8_t;
typedef __attribute__((ext_vector_type(4))) float f32x4_t;

__device__ __forceinline__ unsigned short f2bf(float f) {
    union { float f; unsigned u; } v; v.f = f;
    unsigned r = v.u + 0x7FFFu + ((v.u >> 16) & 1u);  // RNE
    return (unsigned short)(r >> 16);
}

__device__ __forceinline__ unsigned pkbf(float a, float b) {
#if defined(__has_builtin) && __has_builtin(__builtin_amdgcn_cvt_pk_bf16_f32)
    auto v = __builtin_amdgcn_cvt_pk_bf16_f32(a, b);
    union { decltype(v) x; unsigned u; } cv; cv.x = v; return cv.u;
#else
    return (unsigned)f2bf(a) | ((unsigned)f2bf(b) << 16);
#endif
}

#if defined(__has_builtin) && __has_builtin(__builtin_amdgcn_exp2f)
#define EXP2F(x) __builtin_amdgcn_exp2f(x)
#else
#define EXP2F(x) __expf((x) * 0.69314718f)
#endif

#define QSCALE 0.18033688011112042f  // log2(e)/8, folded into Q projection

__device__ __forceinline__ void gl_lds16(const void* g, void* l) {
    __builtin_amdgcn_global_load_lds(
        (const __attribute__((address_space(1))) unsigned int*)g,
        (__attribute__((address_space(3))) unsigned int*)l, 16, 0, 0);
}

// ---------------- fp32 -> bf16 casts (batched) ----------------
__global__ void cvt3(const float* __restrict__ a, const float* __restrict__ b, const float* __restrict__ c,
                     unsigned short* __restrict__ oa, unsigned short* __restrict__ ob, unsigned short* __restrict__ oc,
                     int n4) {
    int i = blockIdx.x * blockDim.x + threadIdx.x;
    const float* s = blockIdx.y == 0 ? a : (blockIdx.y == 1 ? b : c);
    unsigned short* d = blockIdx.y == 0 ? oa : (blockIdx.y == 1 ? ob : oc);
    if (i < n4) {
        float4 v = ((const float4*)s)[i];
        ushort4 o;
        o.x = f2bf(v.x); o.y = f2bf(v.y); o.z = f2bf(v.z); o.w = f2bf(v.w);
        ((ushort4*)d)[i] = o;
    }
}

__global__ void cvt4(const float* __restrict__ a, const float* __restrict__ b,
                     const float* __restrict__ c, const float* __restrict__ e,
                     unsigned short* __restrict__ oa, unsigned short* __restrict__ ob,
                     unsigned short* __restrict__ oc, unsigned short* __restrict__ oe,
                     int n4) {
    int i = blockIdx.x * blockDim.x + threadIdx.x;
    const float* s = blockIdx.y == 0 ? a : (blockIdx.y == 1 ? b : (blockIdx.y == 2 ? c : e));
    unsigned short* d = blockIdx.y == 0 ? oa : (blockIdx.y == 1 ? ob : (blockIdx.y == 2 ? oc : oe));
    if (i < n4) {
        float4 v = ((const float4*)s)[i];
        ushort4 o;
        o.x = f2bf(v.x); o.y = f2bf(v.y); o.z = f2bf(v.z); o.w = f2bf(v.w);
        ((ushort4*)d)[i] = o;
    }
}

// ---------------- mask -> bitmask (1 bit per key) ----------------
__global__ void pack_mask(const int* __restrict__ m, unsigned long long* __restrict__ bits) {
    int g = blockIdx.x * 256 + threadIdx.x;
    unsigned long long bal = __ballot(m[g] != 0);
    if ((threadIdx.x & 63) == 0) bits[g >> 6] = bal;
}

// ---------------- NT GEMM: C[M,N] = (A[M,K] @ B[N,K]^T + bias) * scale ----------------
// OMODE 0: bf16 row-major; 1: bf16 transposed (C^T); 2: f32 row-major
// LDS tiles XOR-swizzled: row r's 16B chunk c holds global chunk c ^ ((r>>1)&3).
template<int OMODE>
__global__ __launch_bounds__(256) void gemm_nt(
    const unsigned short* __restrict__ A,
    const unsigned short* __restrict__ B,
    const float* __restrict__ bias,
    unsigned short* __restrict__ Cb,
    float* __restrict__ Cf,
    int M, int N, int K, float scale)
{
    __shared__ unsigned short As[128 * 32];
    __shared__ unsigned short Bs[128 * 32];
    const int tid = threadIdx.x;
    const int w = tid >> 6, lane = tid & 63;
    const int wr = w >> 1, wc = w & 1;
    const int quad = lane >> 4, l16 = lane & 15;
    const int bn = blockIdx.x, bm = blockIdx.y;

    const int rl = lane >> 2;
    const int cl = (((lane & 3) ^ ((rl >> 1) & 3)) * 8);  // swizzled source column
    const int sw = (l16 >> 1) & 3;                        // reader swizzle
    const int c0 = w * 2;
    const unsigned short* gA = A + (size_t)(bm * 128 + c0 * 16 + rl) * K + cl;
    const unsigned short* gB = B + (size_t)(bn * 128 + c0 * 16 + rl) * K + cl;
    unsigned short* lA = As + c0 * 512 + lane * 8;
    unsigned short* lB = Bs + c0 * 512 + lane * 8;

    f32x4_t acc[4][4] = {};

    for (int k0 = 0; k0 < K; k0 += 32) {
        gl_lds16(gA, lA);
        gl_lds16(gA + (size_t)16 * K, lA + 16 * 32);
        gl_lds16(gB, lB);
        gl_lds16(gB + (size_t)16 * K, lB + 16 * 32);
        gA += 32; gB += 32;
        __syncthreads();
        bf16x8_t af[4], bfr[4];
#pragma unroll
        for (int mi = 0; mi < 4; ++mi)
            af[mi] = *(const bf16x8_t*)(As + (wr * 64 + mi * 16 + l16) * 32 + (quad ^ sw) * 8);
#pragma unroll
        for (int ni = 0; ni < 4; ++ni)
            bfr[ni] = *(const bf16x8_t*)(Bs + (wc * 64 + ni * 16 + l16) * 32 + (quad ^ sw) * 8);
#pragma unroll
        for (int mi = 0; mi < 4; ++mi)
#pragma unroll
            for (int ni = 0; ni < 4; ++ni)
                acc[mi][ni] = __builtin_amdgcn_mfma_f32_16x16x32_bf16(af[mi], bfr[ni], acc[mi][ni], 0, 0, 0);
        __syncthreads();
    }

#pragma unroll
    for (int mi = 0; mi < 4; ++mi) {
#pragma unroll
        for (int ni = 0; ni < 4; ++ni) {
            const int n = bn * 128 + wc * 64 + ni * 16 + l16;
            const int m0 = bm * 128 + wr * 64 + mi * 16 + quad * 4;
            const float bv = bias[n];
            if (OMODE == 1) {
                ushort4 pk;
                pk.x = f2bf((acc[mi][ni][0] + bv) * scale);
                pk.y = f2bf((acc[mi][ni][1] + bv) * scale);
                pk.z = f2bf((acc[mi][ni][2] + bv) * scale);
                pk.w = f2bf((acc[mi][ni][3] + bv) * scale);
                *(ushort4*)(Cb + (size_t)n * M + m0) = pk;
            } else {
#pragma unroll
                for (int r = 0; r < 4; ++r) {
                    const float v = (acc[mi][ni][r] + bv) * scale;
                    if (OMODE == 0) Cb[(size_t)(m0 + r) * N + n] = f2bf(v);
                    else            Cf[(size_t)(m0 + r) * N + n] = v;
                }
            }
        }
    }
}

// ---------------- fused flash attention ----------------
// S^T orientation: scores computed as S^T[key][query] (query = l16 column), so the
// P->PV-operand transform is a 4-lane shuffle within each l16 column (no LDS trip).
__global__ __launch_bounds__(256) void attn_kernel(
    const unsigned short* __restrict__ Qp,   // [M][D] bf16, pre-scaled by log2e/8
    const unsigned short* __restrict__ Kp,   // [M][D] bf16
    const unsigned short* __restrict__ Vt,   // [D][M] bf16 (V^T)
    const unsigned long long* __restrict__ mbits, // [B*S][32] packed mask bits
    unsigned short* __restrict__ Xa)         // [M][D] bf16
{
    __shared__ unsigned short SMEM[8192];    // 16 KB: Ks=SMEM[0..4095], Vs=SMEM[4096..8191]
    unsigned short* const Ks = SMEM;
    unsigned short* const Vs = SMEM + 4096;

    const int tid = threadIdx.x, w = tid >> 6, lane = tid & 63;
    const int quad = lane >> 4, l16 = lane & 15;
    const int bx = blockIdx.x;
    const int h = bx & 15, qt = (bx >> 4) & 15, b = bx >> 8;
    const int q0 = qt * 128;
    const int rl = lane >> 2;
    const int cl = (((lane & 3) ^ ((rl >> 1) & 3)) * 8);
    const int sw = (l16 >> 1) & 3;
    const bool hi16 = (lane & 16) != 0;   // source-select bit (quad&1)
    const bool hi32 = (lane & 32) != 0;   // assembly-select bit (quad>>1)
    const int idxA = (2 * (quad & 1) + (quad >> 1)) * 16 + l16;
    const int idxC = idxA ^ 16;

    // ---- stage 128x64 Q tile (swizzled, 16 chunks across SMEM), pull B-frags ----
#pragma unroll
    for (int i = 0; i < 4; ++i) {
        const int cc = w * 4 + i;
        const int row = b * SDIM + q0 + (cc & 7) * 16 + rl;
        const int col = h * 64 + (cc >> 3) * 32 + cl;
        gl_lds16(Qp + (size_t)row * DDIM + col, SMEM + cc * 512 + lane * 8);
    }
    __syncthreads();
    bf16x8_t aq[2][2];  // [query-group g][kk]: query = w*32+g*16+l16, dk = kk*32+quad*8..
#pragma unroll
    for (int g = 0; g < 2; ++g)
#pragma unroll
        for (int kk = 0; kk < 2; ++kk)
            aq[g][kk] = *(const bf16x8_t*)(SMEM + (kk * 8 + w * 2 + g) * 512 + l16 * 32 + (quad ^ sw) * 8);

    // mask words: query row = q0 + w*32 + g*16 + l16
    const unsigned long long* mq0 = mbits + (size_t)(b * SDIM + q0 + w * 32 + l16) * 32;
    const unsigned long long* mq1 = mq0 + (size_t)16 * 32;

    f32x4_t o[2][4] = {};   // O^T tiles: row=dk(ni*16+quad*4+r), col=query(l16)
    f32x4_t o4[2] = {};     // row sums via ones-A MFMA
    union { unsigned u[4]; bf16x8_t v; } ones;
    ones.u[0] = ones.u[1] = ones.u[2] = ones.u[3] = 0x3F803F80u;

    for (int kt = 0; kt < SDIM / 64; ++kt) {
        __syncthreads();
#pragma unroll
        for (int i = 0; i < 2; ++i) {
            const int cc = w * 2 + i;
            const int rowk = b * SDIM + kt * 64 + (cc & 3) * 16 + rl;
            const int colk = h * 64 + (cc >> 2) * 32 + cl;
            gl_lds16(Kp + (size_t)rowk * DDIM + colk, Ks + cc * 512 + lane * 8);
            const int rowv = h * 64 + (cc & 3) * 16 + rl;
            const int colv = b * SDIM + kt * 64 + (cc >> 2) * 32 + cl;
            gl_lds16(Vt + (size_t)rowv * MDIM + colv, Vs + cc * 512 + lane * 8);
        }
        __syncthreads();

        // per-query mask word for this 64-key tile; pre-shift by quad*4
        const unsigned long long sh0 = mq0[kt] >> (quad * 4);
        const unsigned long long sh1 = mq1[kt] >> (quad * 4);

        // S^T = K Q^T : tile row = key (ni*16+quad*4+r), col = query (l16)
        f32x4_t sf[2][4] = {};
#pragma unroll
        for (int kk = 0; kk < 2; ++kk) {
#pragma unroll
            for (int ni = 0; ni < 4; ++ni) {
                const bf16x8_t ak = *(const bf16x8_t*)(Ks + kk * 2048 + (ni * 16 + l16) * 32 + (quad ^ sw) * 8);
                sf[0][ni] = __builtin_amdgcn_mfma_f32_16x16x32_bf16(ak, aq[0][kk], sf[0][ni], 0, 0, 0);
                sf[1][ni] = __builtin_amdgcn_mfma_f32_16x16x32_bf16(ak, aq[1][kk], sf[1][ni], 0, 0, 0);
            }
        }

        // p = exp2(masked s); pack key-pairs to bf16 dwords
        // P[g][ni][t]: keys ni*16+quad*4+2t..+2t+1, query l16
        unsigned P[2][4][2];
#pragma unroll
        for (int g = 0; g < 2; ++g) {
            const unsigned long long s = g ? sh1 : sh0;
            const unsigned mlo = (unsigned)s, mhi = (unsigned)(s >> 32);
#pragma unroll
            for (int ni = 0; ni < 4; ++ni) {
                const unsigned msel = (ni < 2) ? mlo : mhi;
                const int shf = (ni & 1) * 16;
                float p[4];
#pragma unroll
                for (int r = 0; r < 4; ++r) {
                    const bool on = (msel >> (shf + r)) & 1u;
                    p[r] = EXP2F(on ? sf[g][ni][r] : -1.0e9f);
                }
                P[g][ni][0] = pkbf(p[0], p[1]);
                P[g][ni][1] = pkbf(p[2], p[3]);
            }
        }

        // PV: O^T += V^T * P^T. B-frag (P^T) built by 4-lane column shuffle.
#pragma unroll
        for (int kk2 = 0; kk2 < 2; ++kk2) {
            bf16x8_t va[4];
#pragma unroll
            for (int ni = 0; ni < 4; ++ni)
                va[ni] = *(const bf16x8_t*)(Vs + kk2 * 2048 + (ni * 16 + l16) * 32 + (quad ^ sw) * 8);
#pragma unroll
            for (int g = 0; g < 2; ++g) {
                const unsigned Pa = P[g][kk2 * 2][0], Pb = P[g][kk2 * 2][1];
                const unsigned Pc = P[g][kk2 * 2 + 1][0], Pd = P[g][kk2 * 2 + 1][1];
                const int RA = hi16 ? (int)Pc : (int)Pa;
                const int RB = hi16 ? (int)Pd : (int)Pb;
                const int RC = hi16 ? (int)Pa : (int)Pc;
                const int RD = hi16 ? (int)Pb : (int)Pd;
                const int Av = __shfl(RA, idxA, 64);
                const int Bv = __shfl(RB, idxA, 64);
                const int Cv = __shfl(RC, idxC, 64);
                const int Dv = __shfl(RD, idxC, 64);
                union { unsigned u[4]; bf16x8_t v; } pf;
                pf.u[0] = (unsigned)(hi32 ? Cv : Av);
                pf.u[1] = (unsigned)(hi32 ? Dv : Bv);
                pf.u[2] = (unsigned)(hi32 ? Av : Cv);
                pf.u[3] = (unsigned)(hi32 ? Bv : Dv);
#pragma unroll
                for (int ni = 0; ni < 4; ++ni)
                    o[g][ni] = __builtin_amdgcn_mfma_f32_16x16x32_bf16(va[ni], pf.v, o[g][ni], 0, 0, 0);
                o4[g] = __builtin_amdgcn_mfma_f32_16x16x32_bf16(ones.v, pf.v, o4[g], 0, 0, 0);
            }
        }
    }

    // ---- epilogue: normalize, transpose O^T -> O via per-wave LDS, store ----
    __syncthreads();  // all PV LDS reads done before reuse
    unsigned short* T = SMEM + w * 1152;  // per-wave [16 queries][72 dk] ushorts
#pragma unroll
    for (int g = 0; g < 2; ++g) {
        const float rcp = 1.0f / o4[g][0];  // every reg holds the column's row-sum
#pragma unroll
        for (int ni = 0; ni < 4; ++ni) {
            uint2 pk;
            pk.x = pkbf(o[g][ni][0] * rcp, o[g][ni][1] * rcp);
            pk.y = pkbf(o[g][ni][2] * rcp, o[g][ni][3] * rcp);
            *(uint2*)&T[l16 * 72 + ni * 16 + quad * 4] = pk;
        }
        const int qrow = q0 + w * 32 + g * 16 + (lane >> 2);
        const int dkc = (lane & 3) * 16;
        const bf16x8_t r0 = *(const bf16x8_t*)&T[(lane >> 2) * 72 + dkc];
        const bf16x8_t r1 = *(const bf16x8_t*)&T[(lane >> 2) * 72 + dkc + 8];
        unsigned short* dst = Xa + (size_t)(b * SDIM + qrow) * DDIM + h * 64 + dkc;
        *(bf16x8_t*)dst = r0;
        *(bf16x8_t*)(dst + 8) = r1;
    }
}

extern "C" void kernel_launch(void* const* d_in, const int* in_sizes, int n_in,
                              void* d_out, int out_size, void* d_ws, size_t ws_size,
                              hipStream_t stream)
{
    const float* query = (const float*)d_in[0];
    const float* key   = (const float*)d_in[1];
    const float* value = (const float*)d_in[2];
    const int*   mask  = (const int*)d_in[3];
    const float* Wq = (const float*)d_in[4];  const float* bq = (const float*)d_in[5];
    const float* Wk = (const float*)d_in[6];  const float* bk = (const float*)d_in[7];
    const float* Wv = (const float*)d_in[8];  const float* bv = (const float*)d_in[9];
    const float* Wo = (const float*)d_in[10]; const float* bo = (const float*)d_in[11];

    const size_t MD = (size_t)MDIM * DDIM;
    const size_t DD = (size_t)DDIM * DDIM;

    unsigned short* qb  = (unsigned short*)d_ws;
    unsigned short* kb  = qb + MD;
    unsigned short* vb  = kb + MD;
    unsigned short* wqb = vb + MD;
    unsigned short* wkb = wqb + DD;
    unsigned short* wvb = wkb + DD;
    unsigned short* wob = wvb + DD;
    unsigned short* Qp  = wob + DD;
    unsigned short* Kp  = Qp + MD;
    unsigned short* Vt  = Kp + MD;
    unsigned short* Xa  = Vt + MD;
    unsigned long long* mbits = (unsigned long long*)qb;  // reuse after Q GEMM (2 MB)

    {
        const int n4m = (int)(MD / 4), n4d = (int)(DD / 4);
        dim3 g3((n4m + 255) / 256, 3), g4((n4d + 255) / 256, 4);
        cvt3<<<g3, 256, 0, stream>>>(query, key, value, qb, kb, vb, n4m);
        cvt4<<<g4, 256, 0, stream>>>(Wq, Wk, Wv, Wo, wqb, wkb, wvb, wob, n4d);
    }

    dim3 gg(DDIM / 128, MDIM / 128);
    gemm_nt<0><<<gg, 256, 0, stream>>>(qb, wqb, bq, Qp, nullptr, MDIM, DDIM, DDIM, QSCALE);
    gemm_nt<0><<<gg, 256, 0, stream>>>(kb, wkb, bk, Kp, nullptr, MDIM, DDIM, DDIM, 1.0f);
    gemm_nt<1><<<gg, 256, 0, stream>>>(vb, wvb, bv, Vt, nullptr, MDIM, DDIM, DDIM, 1.0f);

    pack_mask<<<(BDIM * SDIM * SDIM) / 256, 256, 0, stream>>>(mask, mbits);

    attn_kernel<<<BDIM * HDIM * (SDIM / 128), 256, 0, stream>>>(Qp, Kp, Vt, mbits, Xa);

    gemm_nt<2><<<gg, 256, 0, stream>>>(Xa, wob, bo, nullptr, (float*)d_out, MDIM, DDIM, DDIM, 1.0f);
}

// Round 6
// 463.825 us; speedup vs baseline: 1.2015x; 1.0568x over previous
//
#include <hip/hip_runtime.h>

// Problem constants: B=4, S=2048, D=1024, H=16, DK=64
#define BDIM 4
#define SDIM 2048
#define DDIM 1024
#define HDIM 16
#define DKDIM 64
#define MDIM (BDIM*SDIM)   // 8192

typedef __attribute__((ext_vector_type(8))) short bf16x8_t;
typedef __attribute__((ext_vector_type(4))) float f32x4_t;

__device__ __forceinline__ unsigned short f2bf(float f) {
    union { float f; unsigned u; } v; v.f = f;
    unsigned r = v.u + 0x7FFFu + ((v.u >> 16) & 1u);  // RNE
    return (unsigned short)(r >> 16);
}

__device__ __forceinline__ unsigned pkbf(float a, float b) {
#if defined(__has_builtin) && __has_builtin(__builtin_amdgcn_cvt_pk_bf16_f32)
    auto v = __builtin_amdgcn_cvt_pk_bf16_f32(a, b);
    union { decltype(v) x; unsigned u; } cv; cv.x = v; return cv.u;
#else
    return (unsigned)f2bf(a) | ((unsigned)f2bf(b) << 16);
#endif
}

#if defined(__has_builtin) && __has_builtin(__builtin_amdgcn_exp2f)
#define EXP2F(x) __builtin_amdgcn_exp2f(x)
#else
#define EXP2F(x) __expf((x) * 0.69314718f)
#endif

#define QSCALE 0.18033688011112042f  // log2(e)/8, folded into Q projection

__device__ __forceinline__ void gl_lds16(const void* g, void* l) {
    __builtin_amdgcn_global_load_lds(
        (const __attribute__((address_space(1))) unsigned int*)g,
        (__attribute__((address_space(3))) unsigned int*)l, 16, 0, 0);
}

// ---------------- fp32 -> bf16 casts (batched) ----------------
__global__ void cvt3(const float* __restrict__ a, const float* __restrict__ b, const float* __restrict__ c,
                     unsigned short* __restrict__ oa, unsigned short* __restrict__ ob, unsigned short* __restrict__ oc,
                     int n4) {
    int i = blockIdx.x * blockDim.x + threadIdx.x;
    const float* s = blockIdx.y == 0 ? a : (blockIdx.y == 1 ? b : c);
    unsigned short* d = blockIdx.y == 0 ? oa : (blockIdx.y == 1 ? ob : oc);
    if (i < n4) {
        float4 v = ((const float4*)s)[i];
        ushort4 o;
        o.x = f2bf(v.x); o.y = f2bf(v.y); o.z = f2bf(v.z); o.w = f2bf(v.w);
        ((ushort4*)d)[i] = o;
    }
}

__global__ void cvt4(const float* __restrict__ a, const float* __restrict__ b,
                     const float* __restrict__ c, const float* __restrict__ e,
                     unsigned short* __restrict__ oa, unsigned short* __restrict__ ob,
                     unsigned short* __restrict__ oc, unsigned short* __restrict__ oe,
                     int n4) {
    int i = blockIdx.x * blockDim.x + threadIdx.x;
    const float* s = blockIdx.y == 0 ? a : (blockIdx.y == 1 ? b : (blockIdx.y == 2 ? c : e));
    unsigned short* d = blockIdx.y == 0 ? oa : (blockIdx.y == 1 ? ob : (blockIdx.y == 2 ? oc : oe));
    if (i < n4) {
        float4 v = ((const float4*)s)[i];
        ushort4 o;
        o.x = f2bf(v.x); o.y = f2bf(v.y); o.z = f2bf(v.z); o.w = f2bf(v.w);
        ((ushort4*)d)[i] = o;
    }
}

// ---------------- mask -> bitmask (1 bit per key) ----------------
__global__ void pack_mask(const int* __restrict__ m, unsigned long long* __restrict__ bits) {
    int g = blockIdx.x * 256 + threadIdx.x;
    unsigned long long bal = __ballot(m[g] != 0);
    if ((threadIdx.x & 63) == 0) bits[g >> 6] = bal;
}

// ---------------- merged Q/K/V projection GEMMs (z selects stream) ----------------
// C = (A @ W^T + bias) * scale.  z==2 stores transposed (V^T).  Double-buffered staging.
__global__ __launch_bounds__(256) void gemm_qkv(
    const unsigned short* __restrict__ A0, const unsigned short* __restrict__ A1,
    const unsigned short* __restrict__ A2,
    const unsigned short* __restrict__ B0, const unsigned short* __restrict__ B1,
    const unsigned short* __restrict__ B2,
    const float* __restrict__ bi0, const float* __restrict__ bi1, const float* __restrict__ bi2,
    unsigned short* __restrict__ C0, unsigned short* __restrict__ C1,
    unsigned short* __restrict__ C2)
{
    __shared__ unsigned short As[2][128 * 32];
    __shared__ unsigned short Bs[2][128 * 32];
    const int K = DDIM, M = MDIM, N = DDIM;
    const int z = blockIdx.z;
    const unsigned short* A = z == 0 ? A0 : (z == 1 ? A1 : A2);
    const unsigned short* Bw = z == 0 ? B0 : (z == 1 ? B1 : B2);
    const float* bias = z == 0 ? bi0 : (z == 1 ? bi1 : bi2);
    unsigned short* Cb = z == 0 ? C0 : (z == 1 ? C1 : C2);
    const float scale = z == 0 ? QSCALE : 1.0f;

    const int tid = threadIdx.x;
    const int w = tid >> 6, lane = tid & 63;
    const int wr = w >> 1, wc = w & 1;
    const int quad = lane >> 4, l16 = lane & 15;
    const int bn = blockIdx.x, bm = blockIdx.y;

    const int rl = lane >> 2;
    const int cl = (((lane & 3) ^ ((rl >> 1) & 3)) * 8);  // swizzled source column
    const int sw = (l16 >> 1) & 3;                        // reader swizzle
    const int c0 = w * 2;
    const unsigned short* gA = A + (size_t)(bm * 128 + c0 * 16 + rl) * K + cl;
    const unsigned short* gB = Bw + (size_t)(bn * 128 + c0 * 16 + rl) * K + cl;
    const int ldsoff = c0 * 512 + lane * 8;

    f32x4_t acc[4][4] = {};

    // prologue: stage k0=0 into buf 0
    gl_lds16(gA, &As[0][ldsoff]);
    gl_lds16(gA + (size_t)16 * K, &As[0][ldsoff + 16 * 32]);
    gl_lds16(gB, &Bs[0][ldsoff]);
    gl_lds16(gB + (size_t)16 * K, &Bs[0][ldsoff + 16 * 32]);

    int cur = 0;
    for (int k0 = 0; k0 < K; k0 += 32) {
        __syncthreads();   // buf[cur] staged + prior reads of buf[cur] done
        if (k0 + 32 < K) {
            const unsigned short* nA = gA + k0 + 32;
            const unsigned short* nB = gB + k0 + 32;
            gl_lds16(nA, &As[cur ^ 1][ldsoff]);
            gl_lds16(nA + (size_t)16 * K, &As[cur ^ 1][ldsoff + 16 * 32]);
            gl_lds16(nB, &Bs[cur ^ 1][ldsoff]);
            gl_lds16(nB + (size_t)16 * K, &Bs[cur ^ 1][ldsoff + 16 * 32]);
        }
        bf16x8_t af[4], bfr[4];
#pragma unroll
        for (int mi = 0; mi < 4; ++mi)
            af[mi] = *(const bf16x8_t*)(&As[cur][(wr * 64 + mi * 16 + l16) * 32 + (quad ^ sw) * 8]);
#pragma unroll
        for (int ni = 0; ni < 4; ++ni)
            bfr[ni] = *(const bf16x8_t*)(&Bs[cur][(wc * 64 + ni * 16 + l16) * 32 + (quad ^ sw) * 8]);
#pragma unroll
        for (int mi = 0; mi < 4; ++mi)
#pragma unroll
            for (int ni = 0; ni < 4; ++ni)
                acc[mi][ni] = __builtin_amdgcn_mfma_f32_16x16x32_bf16(af[mi], bfr[ni], acc[mi][ni], 0, 0, 0);
        cur ^= 1;
    }

#pragma unroll
    for (int mi = 0; mi < 4; ++mi) {
#pragma unroll
        for (int ni = 0; ni < 4; ++ni) {
            const int n = bn * 128 + wc * 64 + ni * 16 + l16;
            const int m0 = bm * 128 + wr * 64 + mi * 16 + quad * 4;
            const float bv = bias[n];
            if (z == 2) {
                ushort4 pk;
                pk.x = f2bf(acc[mi][ni][0] + bv);
                pk.y = f2bf(acc[mi][ni][1] + bv);
                pk.z = f2bf(acc[mi][ni][2] + bv);
                pk.w = f2bf(acc[mi][ni][3] + bv);
                *(ushort4*)(Cb + (size_t)n * M + m0) = pk;  // V^T
            } else {
#pragma unroll
                for (int r = 0; r < 4; ++r)
                    Cb[(size_t)(m0 + r) * N + n] = f2bf((acc[mi][ni][r] + bv) * scale);
            }
        }
    }
}

// ---------------- output projection GEMM (f32 out, double-buffered) ----------------
__global__ __launch_bounds__(256) void gemm_out(
    const unsigned short* __restrict__ A,
    const unsigned short* __restrict__ Bw,
    const float* __restrict__ bias,
    float* __restrict__ Cf)
{
    __shared__ unsigned short As[2][128 * 32];
    __shared__ unsigned short Bs[2][128 * 32];
    const int K = DDIM, N = DDIM;
    const int tid = threadIdx.x;
    const int w = tid >> 6, lane = tid & 63;
    const int wr = w >> 1, wc = w & 1;
    const int quad = lane >> 4, l16 = lane & 15;
    const int bn = blockIdx.x, bm = blockIdx.y;

    const int rl = lane >> 2;
    const int cl = (((lane & 3) ^ ((rl >> 1) & 3)) * 8);
    const int sw = (l16 >> 1) & 3;
    const int c0 = w * 2;
    const unsigned short* gA = A + (size_t)(bm * 128 + c0 * 16 + rl) * K + cl;
    const unsigned short* gB = Bw + (size_t)(bn * 128 + c0 * 16 + rl) * K + cl;
    const int ldsoff = c0 * 512 + lane * 8;

    f32x4_t acc[4][4] = {};

    gl_lds16(gA, &As[0][ldsoff]);
    gl_lds16(gA + (size_t)16 * K, &As[0][ldsoff + 16 * 32]);
    gl_lds16(gB, &Bs[0][ldsoff]);
    gl_lds16(gB + (size_t)16 * K, &Bs[0][ldsoff + 16 * 32]);

    int cur = 0;
    for (int k0 = 0; k0 < K; k0 += 32) {
        __syncthreads();
        if (k0 + 32 < K) {
            const unsigned short* nA = gA + k0 + 32;
            const unsigned short* nB = gB + k0 + 32;
            gl_lds16(nA, &As[cur ^ 1][ldsoff]);
            gl_lds16(nA + (size_t)16 * K, &As[cur ^ 1][ldsoff + 16 * 32]);
            gl_lds16(nB, &Bs[cur ^ 1][ldsoff]);
            gl_lds16(nB + (size_t)16 * K, &Bs[cur ^ 1][ldsoff + 16 * 32]);
        }
        bf16x8_t af[4], bfr[4];
#pragma unroll
        for (int mi = 0; mi < 4; ++mi)
            af[mi] = *(const bf16x8_t*)(&As[cur][(wr * 64 + mi * 16 + l16) * 32 + (quad ^ sw) * 8]);
#pragma unroll
        for (int ni = 0; ni < 4; ++ni)
            bfr[ni] = *(const bf16x8_t*)(&Bs[cur][(wc * 64 + ni * 16 + l16) * 32 + (quad ^ sw) * 8]);
#pragma unroll
        for (int mi = 0; mi < 4; ++mi)
#pragma unroll
            for (int ni = 0; ni < 4; ++ni)
                acc[mi][ni] = __builtin_amdgcn_mfma_f32_16x16x32_bf16(af[mi], bfr[ni], acc[mi][ni], 0, 0, 0);
        cur ^= 1;
    }

#pragma unroll
    for (int mi = 0; mi < 4; ++mi) {
#pragma unroll
        for (int ni = 0; ni < 4; ++ni) {
            const int n = bn * 128 + wc * 64 + ni * 16 + l16;
            const int m0 = bm * 128 + wr * 64 + mi * 16 + quad * 4;
            const float bv = bias[n];
#pragma unroll
            for (int r = 0; r < 4; ++r)
                Cf[(size_t)(m0 + r) * N + n] = acc[mi][ni][r] + bv;
        }
    }
}

// ---------------- fused flash attention (S^T orientation, double-buffered K/V) ----------------
__global__ __launch_bounds__(256) void attn_kernel(
    const unsigned short* __restrict__ Qp,   // [M][D] bf16, pre-scaled by log2e/8
    const unsigned short* __restrict__ Kp,   // [M][D] bf16
    const unsigned short* __restrict__ Vt,   // [D][M] bf16 (V^T)
    const unsigned long long* __restrict__ mbits, // [B*S][32] packed mask bits
    unsigned short* __restrict__ Xa)         // [M][D] bf16
{
    __shared__ unsigned short SMEM[16384];   // 32 KB: Ks[2][4096] then Vs[2][4096]
    const int tid = threadIdx.x, w = tid >> 6, lane = tid & 63;
    const int quad = lane >> 4, l16 = lane & 15;
    const int bx = blockIdx.x;
    const int h = bx & 15, qt = (bx >> 4) & 15, b = bx >> 8;
    const int q0 = qt * 128;
    const int rl = lane >> 2;
    const int cl = (((lane & 3) ^ ((rl >> 1) & 3)) * 8);
    const int sw = (l16 >> 1) & 3;
    const bool hi16 = (lane & 16) != 0;
    const bool hi32 = (lane & 32) != 0;
    const int idxA = (2 * (quad & 1) + (quad >> 1)) * 16 + l16;
    const int idxC = idxA ^ 16;

    // ---- stage 128x64 Q tile (16 chunks over Ks[0]+Ks[1] region), pull B-frags ----
#pragma unroll
    for (int i = 0; i < 4; ++i) {
        const int cc = w * 4 + i;
        const int row = b * SDIM + q0 + (cc & 7) * 16 + rl;
        const int col = h * 64 + (cc >> 3) * 32 + cl;
        gl_lds16(Qp + (size_t)row * DDIM + col, SMEM + cc * 512 + lane * 8);
    }
    __syncthreads();
    bf16x8_t aq[2][2];
#pragma unroll
    for (int g = 0; g < 2; ++g)
#pragma unroll
        for (int kk = 0; kk < 2; ++kk)
            aq[g][kk] = *(const bf16x8_t*)(SMEM + (kk * 8 + w * 2 + g) * 512 + l16 * 32 + (quad ^ sw) * 8);
    __syncthreads();  // Q reads done before kt=0 overwrites Ks[0]

    const unsigned long long* mq0 = mbits + (size_t)(b * SDIM + q0 + w * 32 + l16) * 32;
    const unsigned long long* mq1 = mq0 + (size_t)16 * 32;

    // stage kt=0 into buffer 0
#pragma unroll
    for (int i = 0; i < 2; ++i) {
        const int cc = w * 2 + i;
        const int rowk = b * SDIM + (cc & 3) * 16 + rl;
        const int colk = h * 64 + (cc >> 2) * 32 + cl;
        gl_lds16(Kp + (size_t)rowk * DDIM + colk, SMEM + cc * 512 + lane * 8);
        const int rowv = h * 64 + (cc & 3) * 16 + rl;
        const int colv = b * SDIM + (cc >> 2) * 32 + cl;
        gl_lds16(Vt + (size_t)rowv * MDIM + colv, SMEM + 8192 + cc * 512 + lane * 8);
    }
    unsigned long long nm0 = mq0[0], nm1 = mq1[0];

    f32x4_t o[2][4] = {};
    f32x4_t o4[2] = {};
    union { unsigned u[4]; bf16x8_t v; } ones;
    ones.u[0] = ones.u[1] = ones.u[2] = ones.u[3] = 0x3F803F80u;

    int cur = 0;
    for (int kt = 0; kt < SDIM / 64; ++kt) {
        __syncthreads();   // buf[cur] staged + previous reads of buf[cur] done

        const unsigned long long sh0 = nm0 >> (quad * 4);
        const unsigned long long sh1 = nm1 >> (quad * 4);

        // prefetch kt+1 into buf[cur^1]; mask words after (their wait implies stage done)
        if (kt + 1 < SDIM / 64) {
            const int nb = cur ^ 1;
#pragma unroll
            for (int i = 0; i < 2; ++i) {
                const int cc = w * 2 + i;
                const int rowk = b * SDIM + (kt + 1) * 64 + (cc & 3) * 16 + rl;
                const int colk = h * 64 + (cc >> 2) * 32 + cl;
                gl_lds16(Kp + (size_t)rowk * DDIM + colk, SMEM + nb * 4096 + cc * 512 + lane * 8);
                const int rowv = h * 64 + (cc & 3) * 16 + rl;
                const int colv = b * SDIM + (kt + 1) * 64 + (cc >> 2) * 32 + cl;
                gl_lds16(Vt + (size_t)rowv * MDIM + colv, SMEM + 8192 + nb * 4096 + cc * 512 + lane * 8);
            }
            nm0 = mq0[kt + 1];
            nm1 = mq1[kt + 1];
        }

        const unsigned short* Ksb = SMEM + cur * 4096;
        const unsigned short* Vsb = SMEM + 8192 + cur * 4096;

        // S^T = K Q^T : row = key (ni*16+quad*4+r), col = query (l16)
        f32x4_t sf[2][4] = {};
#pragma unroll
        for (int kk = 0; kk < 2; ++kk) {
#pragma unroll
            for (int ni = 0; ni < 4; ++ni) {
                const bf16x8_t ak = *(const bf16x8_t*)(Ksb + kk * 2048 + (ni * 16 + l16) * 32 + (quad ^ sw) * 8);
                sf[0][ni] = __builtin_amdgcn_mfma_f32_16x16x32_bf16(ak, aq[0][kk], sf[0][ni], 0, 0, 0);
                sf[1][ni] = __builtin_amdgcn_mfma_f32_16x16x32_bf16(ak, aq[1][kk], sf[1][ni], 0, 0, 0);
            }
        }

        // p = exp2(masked s); pack key-pairs to bf16 dwords
        unsigned P[2][4][2];
#pragma unroll
        for (int g = 0; g < 2; ++g) {
            const unsigned long long s = g ? sh1 : sh0;
            const unsigned mlo = (unsigned)s, mhi = (unsigned)(s >> 32);
#pragma unroll
            for (int ni = 0; ni < 4; ++ni) {
                const unsigned msel = (ni < 2) ? mlo : mhi;
                const int shf = (ni & 1) * 16;
                float p[4];
#pragma unroll
                for (int r = 0; r < 4; ++r) {
                    const bool on = (msel >> (shf + r)) & 1u;
                    p[r] = EXP2F(on ? sf[g][ni][r] : -1.0e9f);
                }
                P[g][ni][0] = pkbf(p[0], p[1]);
                P[g][ni][1] = pkbf(p[2], p[3]);
            }
        }

        // PV: O^T += V^T * P^T. B-frag built by 4-lane column shuffle.
#pragma unroll
        for (int kk2 = 0; kk2 < 2; ++kk2) {
            bf16x8_t va[4];
#pragma unroll
            for (int ni = 0; ni < 4; ++ni)
                va[ni] = *(const bf16x8_t*)(Vsb + kk2 * 2048 + (ni * 16 + l16) * 32 + (quad ^ sw) * 8);
#pragma unroll
            for (int g = 0; g < 2; ++g) {
                const unsigned Pa = P[g][kk2 * 2][0], Pb = P[g][kk2 * 2][1];
                const unsigned Pc = P[g][kk2 * 2 + 1][0], Pd = P[g][kk2 * 2 + 1][1];
                const int RA = hi16 ? (int)Pc : (int)Pa;
                const int RB = hi16 ? (int)Pd : (int)Pb;
                const int RC = hi16 ? (int)Pa : (int)Pc;
                const int RD = hi16 ? (int)Pb : (int)Pd;
                const int Av = __shfl(RA, idxA, 64);
                const int Bv = __shfl(RB, idxA, 64);
                const int Cv = __shfl(RC, idxC, 64);
                const int Dv = __shfl(RD, idxC, 64);
                union { unsigned u[4]; bf16x8_t v; } pf;
                pf.u[0] = (unsigned)(hi32 ? Cv : Av);
                pf.u[1] = (unsigned)(hi32 ? Dv : Bv);
                pf.u[2] = (unsigned)(hi32 ? Av : Cv);
                pf.u[3] = (unsigned)(hi32 ? Bv : Dv);
#pragma unroll
                for (int ni = 0; ni < 4; ++ni)
                    o[g][ni] = __builtin_amdgcn_mfma_f32_16x16x32_bf16(va[ni], pf.v, o[g][ni], 0, 0, 0);
                o4[g] = __builtin_amdgcn_mfma_f32_16x16x32_bf16(ones.v, pf.v, o4[g], 0, 0, 0);
            }
        }
        cur ^= 1;
    }

    // ---- epilogue: normalize, transpose O^T -> O via per-wave LDS, store ----
    __syncthreads();
    unsigned short* T = SMEM + w * 1152;  // per-wave [16 queries][72 dk]
#pragma unroll
    for (int g = 0; g < 2; ++g) {
        const float rcp = 1.0f / o4[g][0];
#pragma unroll
        for (int ni = 0; ni < 4; ++ni) {
            uint2 pk;
            pk.x = pkbf(o[g][ni][0] * rcp, o[g][ni][1] * rcp);
            pk.y = pkbf(o[g][ni][2] * rcp, o[g][ni][3] * rcp);
            *(uint2*)&T[l16 * 72 + ni * 16 + quad * 4] = pk;
        }
        const int qrow = q0 + w * 32 + g * 16 + (lane >> 2);
        const int dkc = (lane & 3) * 16;
        __syncthreads();
        const bf16x8_t r0 = *(const bf16x8_t*)&T[(lane >> 2) * 72 + dkc];
        const bf16x8_t r1 = *(const bf16x8_t*)&T[(lane >> 2) * 72 + dkc + 8];
        unsigned short* dst = Xa + (size_t)(b * SDIM + qrow) * DDIM + h * 64 + dkc;
        *(bf16x8_t*)dst = r0;
        *(bf16x8_t*)(dst + 8) = r1;
        __syncthreads();
    }
}

extern "C" void kernel_launch(void* const* d_in, const int* in_sizes, int n_in,
                              void* d_out, int out_size, void* d_ws, size_t ws_size,
                              hipStream_t stream)
{
    const float* query = (const float*)d_in[0];
    const float* key   = (const float*)d_in[1];
    const float* value = (const float*)d_in[2];
    const int*   mask  = (const int*)d_in[3];
    const float* Wq = (const float*)d_in[4];  const float* bq = (const float*)d_in[5];
    const float* Wk = (const float*)d_in[6];  const float* bk = (const float*)d_in[7];
    const float* Wv = (const float*)d_in[8];  const float* bv = (const float*)d_in[9];
    const float* Wo = (const float*)d_in[10]; const float* bo = (const float*)d_in[11];

    const size_t MD = (size_t)MDIM * DDIM;
    const size_t DD = (size_t)DDIM * DDIM;

    unsigned short* qb  = (unsigned short*)d_ws;
    unsigned short* kb  = qb + MD;
    unsigned short* vb  = kb + MD;
    unsigned short* wqb = vb + MD;
    unsigned short* wkb = wqb + DD;
    unsigned short* wvb = wkb + DD;
    unsigned short* wob = wvb + DD;
    unsigned short* Qp  = wob + DD;
    unsigned short* Kp  = Qp + MD;
    unsigned short* Vt  = Kp + MD;
    unsigned short* Xa  = Vt + MD;
    unsigned long long* mbits = (unsigned long long*)qb;  // reuse after QKV GEMM (2 MB)

    {
        const int n4m = (int)(MD / 4), n4d = (int)(DD / 4);
        dim3 g3((n4m + 255) / 256, 3), g4((n4d + 255) / 256, 4);
        cvt3<<<g3, 256, 0, stream>>>(query, key, value, qb, kb, vb, n4m);
        cvt4<<<g4, 256, 0, stream>>>(Wq, Wk, Wv, Wo, wqb, wkb, wvb, wob, n4d);
    }

    dim3 gq(DDIM / 128, MDIM / 128, 3);
    gemm_qkv<<<gq, 256, 0, stream>>>(qb, kb, vb, wqb, wkb, wvb, bq, bk, bv, Qp, Kp, Vt);

    pack_mask<<<(BDIM * SDIM * SDIM) / 256, 256, 0, stream>>>(mask, mbits);

    attn_kernel<<<BDIM * HDIM * (SDIM / 128), 256, 0, stream>>>(Qp, Kp, Vt, mbits, Xa);

    dim3 gg(DDIM / 128, MDIM / 128);
    gemm_out<<<gg, 256, 0, stream>>>(Xa, wob, bo, (float*)d_out);
}